// Round 8
// baseline (116.437 us; speedup 1.0000x reference)
//
#include <hip/hip_runtime.h>
#include <cstdint>
#include <cstddef>

// ============================================================================
// ProposalTargetLayer (MSDN / Faster-RCNN), gfx950. Round 8.
// Pipeline: k_prep -> k_selfin   (2 dispatches)
//  - k_prep: FOUR threads per roi (gt quarter-split, h = tid>>6 wave-uniform).
//    Each thread: 32 IoU tests (divide-free exact fg test); h<2 additionally
//    one threefry hash (channel h) + vb write. 3040 blocks -> 32 waves/CU.
//  - k_selfin: one block per batch b (16 x 1024). Waves 0-7 = fg channel,
//    8-15 = bg channel. Load pass caches the vb row in REGISTERS (6 uint4/
//    thread) + LDS histogram; scan -> threshold bin; candidates collected
//    from the register cache (no L2 re-read); exact rank -> s_top in LDS;
//    then final phase: wave-per-roi butterfly argmax + transform + store.
// Bit-exact discrete decisions (verified rounds 1-7, absmax 0.0):
//  * fg: round(inter/denom)>=0.5 <=> fmaf(-.5,den,inter) >= (-2^-26)*den
//  * boost: +2.0 iff (fg ^ h) == 1   (h=0 fg/r1 channel, h=1 bg/r2 channel)
//  * top_k tie-break via (valbits<<32)|(~idx) exact ranking
//  * threefry partitionable split/uniform identical to jax.random
//  * argmax: max over (iou_bits<<7)|(127-g) == first strict max
//  * degenerate bg (n_in==0): unmasked argmax of r2 keys (from reg cache)
// ============================================================================

#define THREEFRY_PARTITIONABLE 1

constexpr int kB = 16;
constexpr int kN = 12000;
constexpr int kG = 128;
constexpr int kM = kN + kG;   // 12128
constexpr int kM4 = kM / 4;   // 3032 (exact)
constexpr int kR = 256;
constexpr int kFgQuota = 64;
constexpr unsigned kSeedHi = 0u;
constexpr unsigned kSeedLo = 42u;   // jax.random.key(42)

__device__ __forceinline__ int imin(int a, int b) { return a < b ? a : b; }
__device__ __forceinline__ int imax(int a, int b) { return a > b ? a : b; }

__device__ __forceinline__ unsigned rotl32(unsigned v, int d) {
  return (v << d) | (v >> (32 - d));
}

// Threefry-2x32, 20 rounds, exactly as in jax/_src/prng.py.
__device__ __forceinline__ void tf2x32(unsigned k0, unsigned k1,
                                       unsigned x0, unsigned x1,
                                       unsigned& o0, unsigned& o1) {
  const unsigned k2 = k0 ^ k1 ^ 0x1BD11BDAu;
  x0 += k0; x1 += k1;
#define TF_R(d) x0 += x1; x1 = rotl32(x1, d); x1 ^= x0;
  TF_R(13) TF_R(15) TF_R(26) TF_R(6)
  x0 += k1; x1 += k2 + 1u;
  TF_R(17) TF_R(29) TF_R(16) TF_R(24)
  x0 += k2; x1 += k0 + 2u;
  TF_R(13) TF_R(15) TF_R(26) TF_R(6)
  x0 += k0; x1 += k1 + 3u;
  TF_R(17) TF_R(29) TF_R(16) TF_R(24)
  x0 += k1; x1 += k2 + 4u;
  TF_R(13) TF_R(15) TF_R(26) TF_R(6)
  x0 += k2; x1 += k0 + 5u;
#undef TF_R
  o0 = x0; o1 = x1;
}

// Both keys const-folded (literal inputs), then select by (wave-uniform) h.
__device__ __forceinline__ void derive_key(int which, unsigned& ka, unsigned& kb) {
#if THREEFRY_PARTITIONABLE
  unsigned a0, a1, b0, b1;
  tf2x32(kSeedHi, kSeedLo, 0u, 0u, a0, a1);
  tf2x32(kSeedHi, kSeedLo, 0u, 1u, b0, b1);
  ka = which ? b0 : a0;
  kb = which ? b1 : a1;
#else
  unsigned a0, a1, b0, b1;
  tf2x32(kSeedHi, kSeedLo, 0u, 2u, a0, a1);
  tf2x32(kSeedHi, kSeedLo, 1u, 3u, b0, b1);
  ka = which ? a1 : a0;
  kb = which ? b1 : b0;
#endif
}

__device__ __forceinline__ float bits_to_uniform(unsigned bits) {
  return __uint_as_float((bits >> 9) | 0x3f800000u) - 1.0f;
}

__device__ __forceinline__ float jax_uniform(unsigned ka, unsigned kb, unsigned i) {
#if THREEFRY_PARTITIONABLE
  unsigned o0, o1;
  tf2x32(ka, kb, 0u, i, o0, o1);
  return bits_to_uniform(o0 ^ o1);
#else
  const unsigned H = (unsigned)(kB * kM) / 2u;
  unsigned o0, o1;
  if (i < H) { tf2x32(ka, kb, i, i + H, o0, o1); return bits_to_uniform(o0); }
  else       { tf2x32(ka, kb, i - H, i, o0, o1); return bits_to_uniform(o1); }
#endif
}

// in-mask bin: monotone in value. v in [0x40000000, 0x40400000] (2.0..3.0).
__device__ __forceinline__ unsigned mask_bin(unsigned v) {
  unsigned bn = (v - 0x40000000u) >> 11;
  return bn > 2047u ? 2047u : bn;   // exact-3.0 corner merges into top bin
}

// ---------------------------------------------------------------------------
// Kernel A: 4 threads per roi (gt quarter-split). Block 256 = 64 rois x 4.
// Grid (ceil(kM/64), kB) = (190,16) = 3040 blocks -> 32 waves/CU cap.
// ---------------------------------------------------------------------------
__global__ __launch_bounds__(256) void k_prep(const float* __restrict__ all_rois,
                                              const float* __restrict__ gt_boxes,
                                              unsigned* __restrict__ vb) {
  __shared__ float4 sg[kG];
  __shared__ float sga[kG];
  __shared__ int s_fgp[4][64];
  const int b = blockIdx.y;
  const int tid = threadIdx.x;
  if (tid < kG) {
    const float* gp = gt_boxes + ((size_t)b * kG + tid) * 5;
    const float x0 = gp[0], y0 = gp[1], x1 = gp[2], y1 = gp[3];
    sg[tid] = make_float4(x0, y0, x1, y1);
    sga[tid] = ((x1 - x0) + 1.0f) * ((y1 - y0) + 1.0f);
  }
  const int rl = tid & 63;           // roi within block (= lane)
  const int h = tid >> 6;            // gt quarter 0..3 (wave-uniform)
  const int m = blockIdx.x * 64 + rl;
  const bool valid = (m < kM);
  __syncthreads();

  float bx0 = 0.f, by0 = 0.f, bx1 = 0.f, by1 = 0.f;
  if (valid) {
    if (m < kN) {
      const float* rp = all_rois + ((size_t)b * kN + m) * 5;
      bx0 = rp[1]; by0 = rp[2]; bx1 = rp[3]; by1 = rp[4];
    } else {
      const float4 g4 = sg[m - kN];
      bx0 = g4.x; by0 = g4.y; bx1 = g4.z; by1 = g4.w;
    }
  }
  const float areab = ((bx1 - bx0) + 1.0f) * ((by1 - by0) + 1.0f);

  int fgp = 0;
  const int g0 = h * 32;
#pragma unroll 8
  for (int gg = 0; gg < 32; ++gg) {
    const int g = g0 + gg;
    const float4 g4 = sg[g];
    const float xx0 = fmaxf(bx0, g4.x);
    const float yy0 = fmaxf(by0, g4.y);
    const float xx1 = fminf(bx1, g4.z);
    const float yy1 = fminf(by1, g4.w);
    const float iw = fmaxf((xx1 - xx0) + 1.0f, 0.0f);
    const float ih = fmaxf((yy1 - yy0) + 1.0f, 0.0f);
    const float inter = iw * ih;
    const float denom = (areab + sga[g]) - inter;   // ref op order
    fgp |= (__builtin_fmaf(-0.5f, denom, inter) >= (-0x1p-26f) * denom) ? 1 : 0;
  }
  s_fgp[h][rl] = fgp;
  __syncthreads();
  if (!valid || h >= 2) return;      // no barriers after this point
  const int fg = s_fgp[0][rl] | s_fgp[1][rl] | s_fgp[2][rl] | s_fgp[3][rl];

  unsigned ka, kb;
  derive_key(h, ka, kb);             // h wave-uniform select
  const unsigned i = (unsigned)(b * kM + m);
  const float r = jax_uniform(ka, kb, i);
  // h=0 (r1/fg channel): +2 iff fg.  h=1 (r2/bg channel): +2 iff !fg.
  const float v = (fg ^ h) ? (r + 2.0f) : r;
  vb[(size_t)(h * kB + b) * kM + m] = __float_as_uint(v);
}

// ---------------------------------------------------------------------------
// Kernel B (fused select+final): one block per batch b, 1024 threads.
// Waves 0-7 = fg channel (c=0), waves 8-15 = bg channel (c=1).
// ---------------------------------------------------------------------------
__global__ __launch_bounds__(1024) void k_selfin(const float* __restrict__ all_rois,
                                                 const float* __restrict__ gt_boxes,
                                                 const unsigned* __restrict__ vb,
                                                 float* __restrict__ out) {
  __shared__ float4 sg[kG];                       // 2 KB
  __shared__ float sga[kG];                       // 0.5 KB
  __shared__ float slab[kG];                      // 0.5 KB
  __shared__ int s_hist[2][2048];                 // 16 KB
  __shared__ unsigned long long s_cand[2][1024];  // 16 KB
  __shared__ int s_top[2][kR];                    // 2 KB
  __shared__ int s_scan[2][256];                  // 2 KB
  __shared__ int s_red[16];
  __shared__ unsigned long long s_wmax[16];
  __shared__ int s_nin[2], s_tbin[2], s_cnt[2];

  const int b = blockIdx.x;
  const int tid = threadIdx.x;
  const int w = tid >> 6;            // wave 0..15
  const int lane = tid & 63;
  const int c = tid >> 9;            // channel 0/1 (half-block)
  const int lt = tid & 511;          // tid within half

  // ---- phase 0: stage gt, zero hist/counters ----
  if (tid < kG) {
    const float* gp = gt_boxes + ((size_t)b * kG + tid) * 5;
    const float x0 = gp[0], y0 = gp[1], x1 = gp[2], y1 = gp[3];
    sg[tid] = make_float4(x0, y0, x1, y1);
    sga[tid] = ((x1 - x0) + 1.0f) * ((y1 - y0) + 1.0f);
    slab[tid] = gp[4];
  }
  for (int i = tid; i < 4096; i += 1024) ((int*)s_hist)[i] = 0;
  if (tid < 2) s_cnt[tid] = 0;
  __syncthreads();

  // ---- phase 1: load my channel row, cache in regs, histogram + count ----
  const uint4* src4 = (const uint4*)(vb + (size_t)(c * kB + b) * kM);
  uint4 cache[6];
  int cnt = 0;
#pragma unroll
  for (int k = 0; k < 6; ++k) {
    const int i = lt + (k << 9);
    if (i < kM4) {
      const uint4 u = src4[i];
      cache[k] = u;
#define HBIN(x) if ((x) >= 0x40000000u) { ++cnt; atomicAdd(&s_hist[c][mask_bin(x)], 1); }
      HBIN(u.x) HBIN(u.y) HBIN(u.z) HBIN(u.w)
#undef HBIN
    } else {
      cache[k] = make_uint4(0u, 0u, 0u, 0u);
    }
  }
#pragma unroll
  for (int off = 32; off > 0; off >>= 1) cnt += __shfl_down(cnt, off, 64);
  if (lane == 0) s_red[w] = cnt;
  __syncthreads();   // hist + s_red complete
  if (lt == 0) {     // one thread per half
    int t = 0;
    for (int ww = c * 8; ww < c * 8 + 8; ++ww) t += s_red[ww];
    s_nin[c] = t;
  }
  __syncthreads();
  const int quota = (c == 0) ? kFgQuota : kR;
  const int K = imin(s_nin[c], quota);

  // ---- phase 2: scan 256 descending 8-bin chunks per channel ----
  int s = 0;
  if (lt < 256) {
    const int base = 2048 - 8 * (lt + 1);
#pragma unroll
    for (int j = 0; j < 8; ++j) s += s_hist[c][base + j];
    s_scan[c][lt] = s;
  }
  __syncthreads();
  for (int off = 1; off < 256; off <<= 1) {
    int add = 0;
    if (lt < 256 && lt >= off) add = s_scan[c][lt - off];
    __syncthreads();
    if (lt < 256) s_scan[c][lt] += add;
    __syncthreads();
  }
  if (lt < 256 && K > 0) {
    const int base = 2048 - 8 * (lt + 1);
    const int above = s_scan[c][lt] - s;   // count in bins above my chunk
    int cum = above;
    for (int j = 7; j >= 0; --j) {         // unique crossing: cum < K <= cum+cc
      const int cc = s_hist[c][base + j];
      if (cum < K && cum + cc >= K) s_tbin[c] = base + j;
      cum += cc;
    }
  }
  // degenerate bg (K==0, c==1): per-thread max key from reg cache
  if (c == 1 && K == 0) {
    unsigned long long best = 0ull;
#pragma unroll
    for (int k = 0; k < 6; ++k) {
      const int i = lt + (k << 9);
      if (i < kM4) {
        const unsigned xs[4] = {cache[k].x, cache[k].y, cache[k].z, cache[k].w};
#pragma unroll
        for (int j = 0; j < 4; ++j) {
          const unsigned long long key = ((unsigned long long)xs[j] << 32) |
              (unsigned)(0xFFFFFFFFu - (unsigned)(4 * i + j));
          if (key > best) best = key;
        }
      }
    }
#pragma unroll
    for (int off = 32; off > 0; off >>= 1) {
      const unsigned long long o = __shfl_down(best, off, 64);
      if (o > best) best = o;
    }
    if (lane == 0) s_wmax[w] = best;
  }
  __syncthreads();   // s_tbin + s_wmax visible
  if (tid == 512 && K == 0) {   // c==1 half leader; K here is bg's K
    unsigned long long best = s_wmax[8];
    for (int ww = 9; ww < 16; ++ww) if (s_wmax[ww] > best) best = s_wmax[ww];
    s_top[1][0] = (int)(0xFFFFFFFFu - (unsigned)(best & 0xFFFFFFFFull));
  }

  // ---- phase 3: candidates from register cache ----
  if (K > 0) {
    const unsigned tbin = (unsigned)s_tbin[c];
#pragma unroll
    for (int k = 0; k < 6; ++k) {
      const int i = lt + (k << 9);
      if (i < kM4) {
        const unsigned xs[4] = {cache[k].x, cache[k].y, cache[k].z, cache[k].w};
#pragma unroll
        for (int j = 0; j < 4; ++j) {
          const unsigned x = xs[j];
          if (x >= 0x40000000u && mask_bin(x) >= tbin) {
            const int p = atomicAdd(&s_cnt[c], 1);
            if (p < 1024)
              s_cand[c][p] = ((unsigned long long)x << 32) |
                  (unsigned)(0xFFFFFFFFu - (unsigned)(4 * i + j));
          }
        }
      }
    }
  }
  __syncthreads();
  // ---- phase 4: exact rank among candidates ----
  if (K > 0) {
    const int Nc = imin(s_cnt[c], 1024);
    for (int j = lt; j < Nc; j += 512) {
      const unsigned long long key = s_cand[c][j];
      int rank = 0;
      for (int i = 0; i < Nc; ++i) rank += (s_cand[c][i] > key) ? 1 : 0;
      if (rank < K)
        s_top[c][rank] = (int)(0xFFFFFFFFu - (unsigned)(key & 0xFFFFFFFFull));
    }
  }
  __syncthreads();

  // ---- phase 5: final outputs, wave-per-roi (16 waves x 16 rois) ----
  const int fgc = imin(s_nin[0], kFgQuota);
  const int bgav = imin(imax(s_nin[1], 1), kR);
  float* o_rois = out;                                   // [B,R,5]
  float* o_lab  = out + (size_t)kB * kR * 5;             // [B,R]
  float* o_tgt  = o_lab + (size_t)kB * kR;               // [B,R,4]
  float* o_iw   = o_tgt + (size_t)kB * kR * 4;           // [B,R,4]
  float* o_ow   = o_iw  + (size_t)kB * kR * 4;           // [B,R,4]

  for (int q = 0; q < 16; ++q) {
    const int pos = w * 16 + q;
    const bool isfg = pos < fgc;
    int keep;
    if (isfg) keep = s_top[0][imin(pos, imax(fgc - 1, 0))];
    else      keep = s_top[1][(pos - fgc) % bgav];

    float bx0, by0, bx1, by1;
    if (keep < kN) {
      const float* rp = all_rois + ((size_t)b * kN + keep) * 5;
      bx0 = rp[1]; by0 = rp[2]; bx1 = rp[3]; by1 = rp[4];
    } else {
      const float4 g4 = sg[keep - kN];
      bx0 = g4.x; by0 = g4.y; bx1 = g4.z; by1 = g4.w;
    }
    const float areab = ((bx1 - bx0) + 1.0f) * ((by1 - by0) + 1.0f);

    unsigned long long best = 0ull;
#pragma unroll
    for (int hh = 0; hh < 2; ++hh) {
      const int g = lane + 64 * hh;
      const float4 g4 = sg[g];
      const float xx0 = fmaxf(bx0, g4.x);
      const float yy0 = fmaxf(by0, g4.y);
      const float xx1 = fminf(bx1, g4.z);
      const float yy1 = fminf(by1, g4.w);
      const float iw = fmaxf((xx1 - xx0) + 1.0f, 0.0f);
      const float ih = fmaxf((yy1 - yy0) + 1.0f, 0.0f);
      const float inter = iw * ih;
      const float iou = inter / ((areab + sga[g]) - inter);   // ref-exact
      const unsigned long long key =
          ((unsigned long long)__float_as_uint(iou) << 7) | (unsigned)(127 - g);
      if (key > best) best = key;
    }
#pragma unroll
    for (int off = 1; off < 64; off <<= 1) {
      const unsigned long long o = __shfl_xor(best, off, 64);
      if (o > best) best = o;
    }
    const int a = 127 - (int)(best & 127ull);

    const float4 gt4 = sg[a];
    const float gx0 = gt4.x, gy0 = gt4.y, gx1 = gt4.z, gy1 = gt4.w;
    const float lab = isfg ? slab[a] : 0.0f;
    const float fg4 = (lab > 0.0f) ? 1.0f : 0.0f;

    const float ew = (bx1 - bx0) + 1.0f;
    const float eh = (by1 - by0) + 1.0f;
    const float ecx = bx0 + 0.5f * ew;
    const float ecy = by0 + 0.5f * eh;
    const float gw = (gx1 - gx0) + 1.0f;
    const float gh = (gy1 - gy0) + 1.0f;
    const float gcx = gx0 + 0.5f * gw;
    const float gcy = gy0 + 0.5f * gh;
    const float t0 = ((gcx - ecx) / ew) / 0.1f;
    const float t1 = ((gcy - ecy) / eh) / 0.1f;
    const float t2 = logf(gw / ew) / 0.2f;
    const float t3 = logf(gh / eh) / 0.2f;

    if (lane == 0) {
      const size_t p = (size_t)b * kR + pos;
      o_rois[p * 5 + 0] = (float)b;
      o_rois[p * 5 + 1] = bx0;
      o_rois[p * 5 + 2] = by0;
      o_rois[p * 5 + 3] = bx1;
      o_rois[p * 5 + 4] = by1;
      o_lab[p] = lab;
      o_tgt[p * 4 + 0] = t0 * fg4;
      o_tgt[p * 4 + 1] = t1 * fg4;
      o_tgt[p * 4 + 2] = t2 * fg4;
      o_tgt[p * 4 + 3] = t3 * fg4;
      o_iw[p * 4 + 0] = fg4; o_iw[p * 4 + 1] = fg4;
      o_iw[p * 4 + 2] = fg4; o_iw[p * 4 + 3] = fg4;
      o_ow[p * 4 + 0] = fg4; o_ow[p * 4 + 1] = fg4;
      o_ow[p * 4 + 2] = fg4; o_ow[p * 4 + 3] = fg4;
    }
  }
}

extern "C" void kernel_launch(void* const* d_in, const int* in_sizes, int n_in_args,
                              void* d_out, int out_size, void* d_ws, size_t ws_size,
                              hipStream_t stream) {
  (void)in_sizes; (void)n_in_args; (void)out_size; (void)ws_size;
  const float* all_rois = (const float*)d_in[0];  // [16,12000,5] fp32
  const float* gt_boxes = (const float*)d_in[1];  // [16,128,5] fp32
  float* out = (float*)d_out;

  unsigned* vb = (unsigned*)d_ws;                 // 2*kB*kM u32 = 1552384 B

  dim3 gA((kM + 63) / 64, kB);                    // (190, 16) = 3040 blocks
  k_prep<<<gA, 256, 0, stream>>>(all_rois, gt_boxes, vb);
  k_selfin<<<kB, 1024, 0, stream>>>(all_rois, gt_boxes, vb, out);
}

// Round 9
// 90.059 us; speedup vs baseline: 1.2929x; 1.2929x over previous
//
#include <hip/hip_runtime.h>
#include <cstdint>
#include <cstddef>

// ============================================================================
// ProposalTargetLayer (MSDN / Faster-RCNN), gfx950. Round 9.
// Round 7 structure (best: 87.5us) + scalar-gt k_prep:
//   k_gt -> k_prep -> k_select -> k_final
//  - k_gt: tiny (16x128): SoA gt table [x0|y0|x1|y1|area][128] per batch in
//    ws. Coords bitwise copies; area = ((x1-x0)+1)*((y1-y0)+1) (same formula
//    as the old LDS sga -> bit-identical downstream).
//  - k_prep: 2 threads/roi (gt-half h=0/1, wave-uniform). gt accessed with
//    WAVE-UNIFORM addresses from the SoA table -> compiler scalarizes to
//    s_load (constant cache); inner loop is pure VALU, no LDS (round 7's
//    2 ds_reads/iter were the ~11us floor). fg partials merged via 1KB LDS.
//  - k_select: byte-identical round-7 kernel (1024 thr x 32 blocks).
//  - k_final: byte-identical round-7 kernel (wave-per-roi, 1024 blocks).
// Bit-exact discrete decisions (verified rounds 1-8, absmax 0.0):
//  * fg: round(inter/denom)>=0.5 <=> fmaf(-.5,den,inter) >= (-2^-26)*den
//  * boost: +2.0 iff (fg ^ h) == 1
//  * top_k tie-break via (valbits<<32)|(~idx) exact ranking
//  * threefry partitionable split/uniform identical to jax.random
//  * argmax: max over (iou_bits<<7)|(127-g) == first strict max
// DO NOT fuse select+final into few blocks (round 8: 16 blocks = 47.8us).
// DO NOT widen per-thread work at the cost of grid width (round 4: 192
// blocks = 49.4us).
// ============================================================================

#define THREEFRY_PARTITIONABLE 1

constexpr int kB = 16;
constexpr int kN = 12000;
constexpr int kG = 128;
constexpr int kM = kN + kG;   // 12128
constexpr int kM4 = kM / 4;   // 3032 (exact)
constexpr int kR = 256;
constexpr int kFgQuota = 64;
constexpr unsigned kSeedHi = 0u;
constexpr unsigned kSeedLo = 42u;   // jax.random.key(42)

__device__ __forceinline__ int imin(int a, int b) { return a < b ? a : b; }
__device__ __forceinline__ int imax(int a, int b) { return a > b ? a : b; }

__device__ __forceinline__ unsigned rotl32(unsigned v, int d) {
  return (v << d) | (v >> (32 - d));
}

// Threefry-2x32, 20 rounds, exactly as in jax/_src/prng.py.
__device__ __forceinline__ void tf2x32(unsigned k0, unsigned k1,
                                       unsigned x0, unsigned x1,
                                       unsigned& o0, unsigned& o1) {
  const unsigned k2 = k0 ^ k1 ^ 0x1BD11BDAu;
  x0 += k0; x1 += k1;
#define TF_R(d) x0 += x1; x1 = rotl32(x1, d); x1 ^= x0;
  TF_R(13) TF_R(15) TF_R(26) TF_R(6)
  x0 += k1; x1 += k2 + 1u;
  TF_R(17) TF_R(29) TF_R(16) TF_R(24)
  x0 += k2; x1 += k0 + 2u;
  TF_R(13) TF_R(15) TF_R(26) TF_R(6)
  x0 += k0; x1 += k1 + 3u;
  TF_R(17) TF_R(29) TF_R(16) TF_R(24)
  x0 += k1; x1 += k2 + 4u;
  TF_R(13) TF_R(15) TF_R(26) TF_R(6)
  x0 += k2; x1 += k0 + 5u;
#undef TF_R
  o0 = x0; o1 = x1;
}

// Both keys const-folded (literal inputs), then select by (wave-uniform) h.
__device__ __forceinline__ void derive_key(int which, unsigned& ka, unsigned& kb) {
#if THREEFRY_PARTITIONABLE
  unsigned a0, a1, b0, b1;
  tf2x32(kSeedHi, kSeedLo, 0u, 0u, a0, a1);
  tf2x32(kSeedHi, kSeedLo, 0u, 1u, b0, b1);
  ka = which ? b0 : a0;
  kb = which ? b1 : a1;
#else
  unsigned a0, a1, b0, b1;
  tf2x32(kSeedHi, kSeedLo, 0u, 2u, a0, a1);
  tf2x32(kSeedHi, kSeedLo, 1u, 3u, b0, b1);
  ka = which ? a1 : a0;
  kb = which ? b1 : b0;
#endif
}

__device__ __forceinline__ float bits_to_uniform(unsigned bits) {
  return __uint_as_float((bits >> 9) | 0x3f800000u) - 1.0f;
}

__device__ __forceinline__ float jax_uniform(unsigned ka, unsigned kb, unsigned i) {
#if THREEFRY_PARTITIONABLE
  unsigned o0, o1;
  tf2x32(ka, kb, 0u, i, o0, o1);
  return bits_to_uniform(o0 ^ o1);
#else
  const unsigned H = (unsigned)(kB * kM) / 2u;
  unsigned o0, o1;
  if (i < H) { tf2x32(ka, kb, i, i + H, o0, o1); return bits_to_uniform(o0); }
  else       { tf2x32(ka, kb, i - H, i, o0, o1); return bits_to_uniform(o1); }
#endif
}

// in-mask bin: monotone in value. v in [0x40000000, 0x40400000] (2.0..3.0).
__device__ __forceinline__ unsigned mask_bin(unsigned v) {
  unsigned bn = (v - 0x40000000u) >> 11;
  return bn > 2047u ? 2047u : bn;   // exact-3.0 corner merges into top bin
}

// ---------------------------------------------------------------------------
// Kernel 0: SoA gt table per batch: gts[b][f][g], f = {x0,y0,x1,y1,area}.
// ---------------------------------------------------------------------------
__global__ __launch_bounds__(128) void k_gt(const float* __restrict__ gt_boxes,
                                            float* __restrict__ gts) {
  const int b = blockIdx.x;
  const int g = threadIdx.x;
  const float* gp = gt_boxes + ((size_t)b * kG + g) * 5;
  const float x0 = gp[0], y0 = gp[1], x1 = gp[2], y1 = gp[3];
  float* o = gts + (size_t)b * 5 * kG;
  o[0 * kG + g] = x0;
  o[1 * kG + g] = y0;
  o[2 * kG + g] = x1;
  o[3 * kG + g] = y1;
  o[4 * kG + g] = ((x1 - x0) + 1.0f) * ((y1 - y0) + 1.0f);
}

// ---------------------------------------------------------------------------
// Kernel A: 2 threads per roi (gt-half split). Block 256 thr = 128 rois x 2.
// Grid ((kM+127)/128, kB) = (95,16) = 1520 blocks. gt via scalar loads.
// ---------------------------------------------------------------------------
__global__ __launch_bounds__(256) void k_prep(const float* __restrict__ all_rois,
                                              const float* __restrict__ gts,
                                              unsigned* __restrict__ vb) {
  __shared__ int s_fgp[2][128];
  const int b = blockIdx.y;
  const int tid = threadIdx.x;
  const int rl = tid & 127;          // roi within block
  const int h = tid >> 7;            // gt half 0/1 (wave-uniform)
  const int m = blockIdx.x * 128 + rl;
  const bool valid = (m < kM);
  const float* gb = gts + (size_t)b * 5 * kG;  // uniform base -> s_load

  float bx0 = 0.f, by0 = 0.f, bx1 = 0.f, by1 = 0.f;
  if (valid) {
    if (m < kN) {
      const float* rp = all_rois + ((size_t)b * kN + m) * 5;
      bx0 = rp[1]; by0 = rp[2]; bx1 = rp[3]; by1 = rp[4];
    } else {
      const int g = m - kN;          // per-lane (vector) load, last block only
      bx0 = gb[0 * kG + g]; by0 = gb[1 * kG + g];
      bx1 = gb[2 * kG + g]; by1 = gb[3 * kG + g];
    }
  }
  const float areab = ((bx1 - bx0) + 1.0f) * ((by1 - by0) + 1.0f);

  int fgp = 0;
  const int g0 = h * 64;
#pragma unroll 8
  for (int gg = 0; gg < 64; ++gg) {
    const int g = g0 + gg;           // uniform -> all gt operands in SGPRs
    const float gx0 = gb[0 * kG + g];
    const float gy0 = gb[1 * kG + g];
    const float gx1 = gb[2 * kG + g];
    const float gy1 = gb[3 * kG + g];
    const float ga  = gb[4 * kG + g];
    const float xx0 = fmaxf(bx0, gx0);
    const float yy0 = fmaxf(by0, gy0);
    const float xx1 = fminf(bx1, gx1);
    const float yy1 = fminf(by1, gy1);
    const float iw = fmaxf((xx1 - xx0) + 1.0f, 0.0f);
    const float ih = fmaxf((yy1 - yy0) + 1.0f, 0.0f);
    const float inter = iw * ih;
    const float denom = (areab + ga) - inter;   // ref op order
    fgp |= (__builtin_fmaf(-0.5f, denom, inter) >= (-0x1p-26f) * denom) ? 1 : 0;
  }
  s_fgp[h][rl] = fgp;
  __syncthreads();
  if (!valid) return;
  const int fg = s_fgp[0][rl] | s_fgp[1][rl];   // exists-g over both halves

  unsigned ka, kb;
  derive_key(h, ka, kb);                        // h wave-uniform select
  const unsigned i = (unsigned)(b * kM + m);
  const float r = jax_uniform(ka, kb, i);
  // h=0 (r1/fg channel): +2 iff fg.  h=1 (r2/bg channel): +2 iff !fg.
  const float v = (fg ^ h) ? (r + 2.0f) : r;
  vb[(size_t)(h * kB + b) * kM + m] = __float_as_uint(v);
}

// block reduce over nw waves (nw <= 16)
__device__ __forceinline__ int block_reduce_sum_w(int v, int* s_red, int tid, int nw) {
#pragma unroll
  for (int off = 32; off > 0; off >>= 1) v += __shfl_down(v, off, 64);
  __syncthreads();
  if ((tid & 63) == 0) s_red[tid >> 6] = v;
  __syncthreads();
  int t = 0;
  for (int w = 0; w < nw; ++w) t += s_red[w];
  return t;
}

// ---------------------------------------------------------------------------
// Kernel B: one block per (which, b), 1024 threads.  (round-7 verified)
// ---------------------------------------------------------------------------
__global__ __launch_bounds__(1024) void k_select(const unsigned* __restrict__ vb,
                                                 int* __restrict__ topidx,
                                                 int* __restrict__ nin) {
  __shared__ int s_hist[2048];                  // 8 KB
  __shared__ unsigned long long s_cand[1024];   // 8 KB
  __shared__ int s_scan[256];
  __shared__ int s_red[16];
  __shared__ unsigned long long s_wmax[16];
  __shared__ int s_tbin, s_cnt;

  const int which = blockIdx.x;
  const int b = blockIdx.y;
  const int tid = threadIdx.x;
  const unsigned* src = vb + (size_t)(which * kB + b) * kM;
  const uint4* src4 = (const uint4*)src;
  int* dst = topidx + (size_t)(which * kB + b) * kR;

  for (int i = tid; i < 2048; i += 1024) s_hist[i] = 0;
  if (tid == 0) s_cnt = 0;
  __syncthreads();

  // pass 1: load (L2-hot) + histogram of in-mask values (3 uint4/thread)
  for (int i = tid; i < kM4; i += 1024) {
    const uint4 u = src4[i];
#define HBIN(x) if ((x) >= 0x40000000u) atomicAdd(&s_hist[mask_bin(x)], 1);
    HBIN(u.x) HBIN(u.y) HBIN(u.z) HBIN(u.w)
#undef HBIN
  }
  __syncthreads();

  // chunk sums: first 256 threads own descending 8-bin chunks
  int s = 0;
  if (tid < 256) {
    const int base = 2048 - 8 * (tid + 1);
#pragma unroll
    for (int j = 0; j < 8; ++j) s += s_hist[base + j];
    s_scan[tid] = s;
  }
  const int n_in = block_reduce_sum_w((tid < 256) ? s : 0, s_red, tid, 16);
  if (tid == 0) nin[which * kB + b] = n_in;
  const int quota = (which == 0) ? kFgQuota : kR;
  const int K = imin(n_in, quota);

  if (K == 0) {
    if (which == 0) return;  // fgc==0 -> fg slots never read
    // bg degenerate: reference takes top of UNMASKED r2 -> plain argmax.
    unsigned long long best = 0ull;
    for (int m = tid; m < kM; m += 1024) {
      const unsigned long long key =
          ((unsigned long long)src[m] << 32) | (unsigned)(0xFFFFFFFFu - (unsigned)m);
      if (key > best) best = key;
    }
#pragma unroll
    for (int off = 32; off > 0; off >>= 1) {
      const unsigned long long o = __shfl_down(best, off, 64);
      if (o > best) best = o;
    }
    __syncthreads();
    if ((tid & 63) == 0) s_wmax[tid >> 6] = best;
    __syncthreads();
    if (tid == 0) {
      for (int w = 1; w < 16; ++w) if (s_wmax[w] > best) best = s_wmax[w];
      dst[0] = (int)(0xFFFFFFFFu - (unsigned)(best & 0xFFFFFFFFull));
    }
    return;
  }

  // inclusive scan over the 256 descending chunk sums -> threshold bin
  __syncthreads();
  for (int off = 1; off < 256; off <<= 1) {
    int add = 0;
    if (tid < 256 && tid >= off) add = s_scan[tid - off];
    __syncthreads();
    if (tid < 256) s_scan[tid] += add;
    __syncthreads();
  }
  if (tid < 256) {
    const int base = 2048 - 8 * (tid + 1);
    int s2 = 0;
#pragma unroll
    for (int j = 0; j < 8; ++j) s2 += s_hist[base + j];
    const int above = s_scan[tid] - s2;  // count in bins above my chunk
    int cum = above;
    for (int j = 7; j >= 0; --j) {       // unique crossing: cum < K <= cum+c
      const int c = s_hist[base + j];
      if (cum < K && cum + c >= K) s_tbin = base + j;
      cum += c;
    }
  }
  __syncthreads();
  const unsigned tbin = (unsigned)s_tbin;

  // pass 2: filtered re-read (L2-hot) -> candidates (~K + lambda)
  for (int i = tid; i < kM4; i += 1024) {
    const uint4 u = src4[i];
#define CAND(x, j)                                                         \
    if ((x) >= 0x40000000u && mask_bin(x) >= tbin) {                       \
      const int p = atomicAdd(&s_cnt, 1);                                  \
      if (p < 1024)                                                        \
        s_cand[p] = ((unsigned long long)(x) << 32) |                      \
                    (unsigned)(0xFFFFFFFFu - (unsigned)(4 * i + (j)));     \
    }
    CAND(u.x, 0) CAND(u.y, 1) CAND(u.z, 2) CAND(u.w, 3)
#undef CAND
  }
  __syncthreads();
  const int Nc = imin(s_cnt, 1024);

  // exact rank among candidates (keys pairwise distinct)
  for (int j = tid; j < Nc; j += 1024) {
    const unsigned long long key = s_cand[j];
    int rank = 0;
    for (int i = 0; i < Nc; ++i) rank += (s_cand[i] > key) ? 1 : 0;
    if (rank < K)
      dst[rank] = (int)(0xFFFFFFFFu - (unsigned)(key & 0xFFFFFFFFull));
  }
}

// ---------------------------------------------------------------------------
// Kernel C: one WAVE per output roi (4096 waves, 1024 blocks x 256).
// (round-7 verified)
// ---------------------------------------------------------------------------
__global__ __launch_bounds__(256) void k_final(const float* __restrict__ all_rois,
                                               const float* __restrict__ gt_boxes,
                                               const int* __restrict__ topidx,
                                               const int* __restrict__ nin,
                                               float* __restrict__ out) {
  const int lane = threadIdx.x & 63;
  const int idx = (blockIdx.x << 2) | (threadIdx.x >> 6);  // roi id 0..4095
  const int b = idx >> 8;
  const int pos = idx & 255;

  const int fgc = imin(nin[b], kFgQuota);
  const int bgav = imin(imax(nin[kB + b], 1), kR);
  const bool isfg = pos < fgc;
  int keep;
  if (isfg) keep = topidx[(size_t)b * kR + imin(pos, imax(fgc - 1, 0))];
  else      keep = topidx[(size_t)(kB + b) * kR + (pos - fgc) % bgav];

  const float* bp = (keep < kN) ? (all_rois + ((size_t)b * kN + keep) * 5 + 1)
                                : (gt_boxes + ((size_t)b * kG + (keep - kN)) * 5);
  const float bx0 = bp[0], by0 = bp[1], bx1 = bp[2], by1 = bp[3];
  const float areab = ((bx1 - bx0) + 1.0f) * ((by1 - by0) + 1.0f);

  unsigned long long best = 0ull;
#pragma unroll
  for (int h = 0; h < 2; ++h) {
    const int g = lane + 64 * h;
    const float* gp = gt_boxes + ((size_t)b * kG + g) * 5;
    const float gx0 = gp[0], gy0 = gp[1], gx1 = gp[2], gy1 = gp[3];
    const float ga = ((gx1 - gx0) + 1.0f) * ((gy1 - gy0) + 1.0f);
    const float xx0 = fmaxf(bx0, gx0);
    const float yy0 = fmaxf(by0, gy0);
    const float xx1 = fminf(bx1, gx1);
    const float yy1 = fminf(by1, gy1);
    const float iw = fmaxf((xx1 - xx0) + 1.0f, 0.0f);
    const float ih = fmaxf((yy1 - yy0) + 1.0f, 0.0f);
    const float inter = iw * ih;
    const float iou = inter / ((areab + ga) - inter);   // ref-exact f32 div
    const unsigned long long key =
        ((unsigned long long)__float_as_uint(iou) << 7) | (unsigned)(127 - g);
    if (key > best) best = key;
  }
#pragma unroll
  for (int off = 1; off < 64; off <<= 1) {
    const unsigned long long o = __shfl_xor(best, off, 64);
    if (o > best) best = o;
  }
  const int a = 127 - (int)(best & 127ull);

  const float* gp = gt_boxes + ((size_t)b * kG + a) * 5;
  const float gx0 = gp[0], gy0 = gp[1], gx1 = gp[2], gy1 = gp[3];
  const float lab = isfg ? gp[4] : 0.0f;
  const float fg4 = (lab > 0.0f) ? 1.0f : 0.0f;

  const float ew = (bx1 - bx0) + 1.0f;
  const float eh = (by1 - by0) + 1.0f;
  const float ecx = bx0 + 0.5f * ew;
  const float ecy = by0 + 0.5f * eh;
  const float gw = (gx1 - gx0) + 1.0f;
  const float gh = (gy1 - gy0) + 1.0f;
  const float gcx = gx0 + 0.5f * gw;
  const float gcy = gy0 + 0.5f * gh;
  const float t0 = ((gcx - ecx) / ew) / 0.1f;
  const float t1 = ((gcy - ecy) / eh) / 0.1f;
  const float t2 = logf(gw / ew) / 0.2f;
  const float t3 = logf(gh / eh) / 0.2f;

  if (lane == 0) {
    float* o_rois = out;                                   // [B,R,5]
    float* o_lab  = out + (size_t)kB * kR * 5;             // [B,R]
    float* o_tgt  = o_lab + (size_t)kB * kR;               // [B,R,4]
    float* o_iw   = o_tgt + (size_t)kB * kR * 4;           // [B,R,4]
    float* o_ow   = o_iw  + (size_t)kB * kR * 4;           // [B,R,4]
    const size_t p = (size_t)b * kR + pos;
    o_rois[p * 5 + 0] = (float)b;
    o_rois[p * 5 + 1] = bx0;
    o_rois[p * 5 + 2] = by0;
    o_rois[p * 5 + 3] = bx1;
    o_rois[p * 5 + 4] = by1;
    o_lab[p] = lab;
    o_tgt[p * 4 + 0] = t0 * fg4;
    o_tgt[p * 4 + 1] = t1 * fg4;
    o_tgt[p * 4 + 2] = t2 * fg4;
    o_tgt[p * 4 + 3] = t3 * fg4;
    o_iw[p * 4 + 0] = fg4; o_iw[p * 4 + 1] = fg4;
    o_iw[p * 4 + 2] = fg4; o_iw[p * 4 + 3] = fg4;
    o_ow[p * 4 + 0] = fg4; o_ow[p * 4 + 1] = fg4;
    o_ow[p * 4 + 2] = fg4; o_ow[p * 4 + 3] = fg4;
  }
}

extern "C" void kernel_launch(void* const* d_in, const int* in_sizes, int n_in_args,
                              void* d_out, int out_size, void* d_ws, size_t ws_size,
                              hipStream_t stream) {
  (void)in_sizes; (void)n_in_args; (void)out_size; (void)ws_size;
  const float* all_rois = (const float*)d_in[0];  // [16,12000,5] fp32
  const float* gt_boxes = (const float*)d_in[1];  // [16,128,5] fp32
  float* out = (float*)d_out;

  char* ws = (char*)d_ws;
  unsigned* vb = (unsigned*)ws;                   // 2*kB*kM u32 = 1552384 B
  float* gts   = (float*)(ws + 1572864);          // 16*5*128 f32 = 40960 B
  int* topidx  = (int*)(ws + 1572864 + 40960);    // 2*kB*kR int = 32 KB
  int* nin     = (int*)(ws + 1572864 + 40960 + 32768); // 32 int

  k_gt<<<kB, 128, 0, stream>>>(gt_boxes, gts);
  dim3 gA((kM + 127) / 128, kB);                  // (95, 16) = 1520 blocks
  k_prep<<<gA, 256, 0, stream>>>(all_rois, gts, vb);
  dim3 gB(2, kB);
  k_select<<<gB, 1024, 0, stream>>>(vb, topidx, nin);
  k_final<<<1024, 256, 0, stream>>>(all_rois, gt_boxes, topidx, nin, out);
}

// Round 10
// 88.662 us; speedup vs baseline: 1.3133x; 1.0158x over previous
//
#include <hip/hip_runtime.h>
#include <cstdint>
#include <cstddef>

// ============================================================================
// ProposalTargetLayer (MSDN / Faster-RCNN), gfx950. Round 10.
// Round-7 pipeline (best measured: 87.5us), two model-driven cuts:
//   k_prep -> k_select -> k_final   (3 dispatches)
//  - k_prep: 2 threads/roi (gt-half h=0/1), gt float4 in LDS; gt AREA now
//    computed INLINE (identical fp32 expression as before -> bit-exact),
//    deleting the ds_read_b32 per iter: LDS issue 1140->768 cyc/wave
//    (the loop is LDS-bound; VALU has slack).
//  - k_select: 1024 thr x 32 blocks; pass-1 caches its 3 uint4/thread in
//    REGISTERS and pass-2 candidates come from the cache (no 2nd L2 sweep).
//    Reg-cache logic identical to round 8's (proven); block count stays 32.
//  - k_final: byte-identical round-7 kernel (wave-per-roi, 1024 blocks).
// Bit-exact discrete decisions (verified rounds 1-9, absmax 0.0):
//  * fg: round(inter/denom)>=0.5 <=> fmaf(-.5,den,inter) >= (-2^-26)*den
//  * boost: +2.0 iff (fg ^ h) == 1
//  * top_k tie-break via (valbits<<32)|(~idx) exact ranking
//  * threefry partitionable split/uniform identical to jax.random
//  * argmax: max over (iou_bits<<7)|(127-g) == first strict max
// Hard-won structure rules:
//  - DO NOT fuse select+final into few blocks (R8: 16 blocks = 47.8us).
//  - DO NOT trade grid width for per-thread work (R4: 192 blocks = 49.4us).
//  - DO NOT add a staging dispatch for scalar gt (R9: +2.6us net).
// ============================================================================

#define THREEFRY_PARTITIONABLE 1

constexpr int kB = 16;
constexpr int kN = 12000;
constexpr int kG = 128;
constexpr int kM = kN + kG;   // 12128
constexpr int kM4 = kM / 4;   // 3032 (exact)
constexpr int kR = 256;
constexpr int kFgQuota = 64;
constexpr unsigned kSeedHi = 0u;
constexpr unsigned kSeedLo = 42u;   // jax.random.key(42)

__device__ __forceinline__ int imin(int a, int b) { return a < b ? a : b; }
__device__ __forceinline__ int imax(int a, int b) { return a > b ? a : b; }

__device__ __forceinline__ unsigned rotl32(unsigned v, int d) {
  return (v << d) | (v >> (32 - d));
}

// Threefry-2x32, 20 rounds, exactly as in jax/_src/prng.py.
__device__ __forceinline__ void tf2x32(unsigned k0, unsigned k1,
                                       unsigned x0, unsigned x1,
                                       unsigned& o0, unsigned& o1) {
  const unsigned k2 = k0 ^ k1 ^ 0x1BD11BDAu;
  x0 += k0; x1 += k1;
#define TF_R(d) x0 += x1; x1 = rotl32(x1, d); x1 ^= x0;
  TF_R(13) TF_R(15) TF_R(26) TF_R(6)
  x0 += k1; x1 += k2 + 1u;
  TF_R(17) TF_R(29) TF_R(16) TF_R(24)
  x0 += k2; x1 += k0 + 2u;
  TF_R(13) TF_R(15) TF_R(26) TF_R(6)
  x0 += k0; x1 += k1 + 3u;
  TF_R(17) TF_R(29) TF_R(16) TF_R(24)
  x0 += k1; x1 += k2 + 4u;
  TF_R(13) TF_R(15) TF_R(26) TF_R(6)
  x0 += k2; x1 += k0 + 5u;
#undef TF_R
  o0 = x0; o1 = x1;
}

// Both keys const-folded (literal inputs), then select by (wave-uniform) h.
__device__ __forceinline__ void derive_key(int which, unsigned& ka, unsigned& kb) {
#if THREEFRY_PARTITIONABLE
  unsigned a0, a1, b0, b1;
  tf2x32(kSeedHi, kSeedLo, 0u, 0u, a0, a1);
  tf2x32(kSeedHi, kSeedLo, 0u, 1u, b0, b1);
  ka = which ? b0 : a0;
  kb = which ? b1 : a1;
#else
  unsigned a0, a1, b0, b1;
  tf2x32(kSeedHi, kSeedLo, 0u, 2u, a0, a1);
  tf2x32(kSeedHi, kSeedLo, 1u, 3u, b0, b1);
  ka = which ? a1 : a0;
  kb = which ? b1 : b0;
#endif
}

__device__ __forceinline__ float bits_to_uniform(unsigned bits) {
  return __uint_as_float((bits >> 9) | 0x3f800000u) - 1.0f;
}

__device__ __forceinline__ float jax_uniform(unsigned ka, unsigned kb, unsigned i) {
#if THREEFRY_PARTITIONABLE
  unsigned o0, o1;
  tf2x32(ka, kb, 0u, i, o0, o1);
  return bits_to_uniform(o0 ^ o1);
#else
  const unsigned H = (unsigned)(kB * kM) / 2u;
  unsigned o0, o1;
  if (i < H) { tf2x32(ka, kb, i, i + H, o0, o1); return bits_to_uniform(o0); }
  else       { tf2x32(ka, kb, i - H, i, o0, o1); return bits_to_uniform(o1); }
#endif
}

// in-mask bin: monotone in value. v in [0x40000000, 0x40400000] (2.0..3.0).
__device__ __forceinline__ unsigned mask_bin(unsigned v) {
  unsigned bn = (v - 0x40000000u) >> 11;
  return bn > 2047u ? 2047u : bn;   // exact-3.0 corner merges into top bin
}

// ---------------------------------------------------------------------------
// Kernel A: 2 threads per roi (gt-half split). Block 256 thr = 128 rois x 2.
// Grid ((kM+127)/128, kB) = (95,16) = 1520 blocks -> ~6 waves/SIMD.
// gt area computed inline (same fp32 expression as the reference's area_g).
// ---------------------------------------------------------------------------
__global__ __launch_bounds__(256) void k_prep(const float* __restrict__ all_rois,
                                              const float* __restrict__ gt_boxes,
                                              unsigned* __restrict__ vb) {
  __shared__ float4 sg[kG];
  __shared__ int s_fgp[2][128];
  const int b = blockIdx.y;
  const int tid = threadIdx.x;
  if (tid < kG) {
    const float* gp = gt_boxes + ((size_t)b * kG + tid) * 5;
    sg[tid] = make_float4(gp[0], gp[1], gp[2], gp[3]);
  }
  const int rl = tid & 127;          // roi within block
  const int h = tid >> 7;            // gt half 0/1 (wave-uniform)
  const int m = blockIdx.x * 128 + rl;
  const bool valid = (m < kM);
  __syncthreads();

  float bx0 = 0.f, by0 = 0.f, bx1 = 0.f, by1 = 0.f;
  if (valid) {
    if (m < kN) {
      const float* rp = all_rois + ((size_t)b * kN + m) * 5;
      bx0 = rp[1]; by0 = rp[2]; bx1 = rp[3]; by1 = rp[4];
    } else {
      const float4 g4 = sg[m - kN];
      bx0 = g4.x; by0 = g4.y; bx1 = g4.z; by1 = g4.w;
    }
  }
  const float areab = ((bx1 - bx0) + 1.0f) * ((by1 - by0) + 1.0f);

  int fgp = 0;
  const int g0 = h * 64;
#pragma unroll 8
  for (int gg = 0; gg < 64; ++gg) {
    const float4 g4 = sg[g0 + gg];
    // inline gt area: identical fp32 expression as reference area_g
    const float ga = ((g4.z - g4.x) + 1.0f) * ((g4.w - g4.y) + 1.0f);
    const float xx0 = fmaxf(bx0, g4.x);
    const float yy0 = fmaxf(by0, g4.y);
    const float xx1 = fminf(bx1, g4.z);
    const float yy1 = fminf(by1, g4.w);
    const float iw = fmaxf((xx1 - xx0) + 1.0f, 0.0f);
    const float ih = fmaxf((yy1 - yy0) + 1.0f, 0.0f);
    const float inter = iw * ih;
    const float denom = (areab + ga) - inter;   // ref op order
    fgp |= (__builtin_fmaf(-0.5f, denom, inter) >= (-0x1p-26f) * denom) ? 1 : 0;
  }
  s_fgp[h][rl] = fgp;
  __syncthreads();
  if (!valid) return;
  const int fg = s_fgp[0][rl] | s_fgp[1][rl];   // exists-g over both halves

  unsigned ka, kb;
  derive_key(h, ka, kb);                        // h wave-uniform select
  const unsigned i = (unsigned)(b * kM + m);
  const float r = jax_uniform(ka, kb, i);
  // h=0 (r1/fg channel): +2 iff fg.  h=1 (r2/bg channel): +2 iff !fg.
  const float v = (fg ^ h) ? (r + 2.0f) : r;
  vb[(size_t)(h * kB + b) * kM + m] = __float_as_uint(v);
}

// block reduce over nw waves (nw <= 16)
__device__ __forceinline__ int block_reduce_sum_w(int v, int* s_red, int tid, int nw) {
#pragma unroll
  for (int off = 32; off > 0; off >>= 1) v += __shfl_down(v, off, 64);
  __syncthreads();
  if ((tid & 63) == 0) s_red[tid >> 6] = v;
  __syncthreads();
  int t = 0;
  for (int w = 0; w < nw; ++w) t += s_red[w];
  return t;
}

// ---------------------------------------------------------------------------
// Kernel B: one block per (which, b), 1024 threads. Pass-1 register cache
// (3 uint4/thread) feeds pass-2 candidate collection (no 2nd L2 sweep).
// ---------------------------------------------------------------------------
__global__ __launch_bounds__(1024) void k_select(const unsigned* __restrict__ vb,
                                                 int* __restrict__ topidx,
                                                 int* __restrict__ nin) {
  __shared__ int s_hist[2048];                  // 8 KB
  __shared__ unsigned long long s_cand[1024];   // 8 KB
  __shared__ int s_scan[256];
  __shared__ int s_red[16];
  __shared__ unsigned long long s_wmax[16];
  __shared__ int s_tbin, s_cnt;

  const int which = blockIdx.x;
  const int b = blockIdx.y;
  const int tid = threadIdx.x;
  const unsigned* src = vb + (size_t)(which * kB + b) * kM;
  const uint4* src4 = (const uint4*)src;
  int* dst = topidx + (size_t)(which * kB + b) * kR;

  for (int i = tid; i < 2048; i += 1024) s_hist[i] = 0;
  if (tid == 0) s_cnt = 0;
  __syncthreads();

  // pass 1: load (L2-hot) into register cache + histogram of in-mask values
  uint4 cache[3];
#pragma unroll
  for (int k = 0; k < 3; ++k) {
    const int i = tid + (k << 10);
    if (i < kM4) {
      const uint4 u = src4[i];
      cache[k] = u;
#define HBIN(x) if ((x) >= 0x40000000u) atomicAdd(&s_hist[mask_bin(x)], 1);
      HBIN(u.x) HBIN(u.y) HBIN(u.z) HBIN(u.w)
#undef HBIN
    } else {
      cache[k] = make_uint4(0u, 0u, 0u, 0u);
    }
  }
  __syncthreads();

  // chunk sums: first 256 threads own descending 8-bin chunks
  int s = 0;
  if (tid < 256) {
    const int base = 2048 - 8 * (tid + 1);
#pragma unroll
    for (int j = 0; j < 8; ++j) s += s_hist[base + j];
    s_scan[tid] = s;
  }
  const int n_in = block_reduce_sum_w((tid < 256) ? s : 0, s_red, tid, 16);
  if (tid == 0) nin[which * kB + b] = n_in;
  const int quota = (which == 0) ? kFgQuota : kR;
  const int K = imin(n_in, quota);

  if (K == 0) {
    if (which == 0) return;  // fgc==0 -> fg slots never read
    // bg degenerate: reference takes top of UNMASKED r2 -> plain argmax.
    unsigned long long best = 0ull;
    for (int m = tid; m < kM; m += 1024) {
      const unsigned long long key =
          ((unsigned long long)src[m] << 32) | (unsigned)(0xFFFFFFFFu - (unsigned)m);
      if (key > best) best = key;
    }
#pragma unroll
    for (int off = 32; off > 0; off >>= 1) {
      const unsigned long long o = __shfl_down(best, off, 64);
      if (o > best) best = o;
    }
    __syncthreads();
    if ((tid & 63) == 0) s_wmax[tid >> 6] = best;
    __syncthreads();
    if (tid == 0) {
      for (int w = 1; w < 16; ++w) if (s_wmax[w] > best) best = s_wmax[w];
      dst[0] = (int)(0xFFFFFFFFu - (unsigned)(best & 0xFFFFFFFFull));
    }
    return;
  }

  // inclusive scan over the 256 descending chunk sums -> threshold bin
  __syncthreads();
  for (int off = 1; off < 256; off <<= 1) {
    int add = 0;
    if (tid < 256 && tid >= off) add = s_scan[tid - off];
    __syncthreads();
    if (tid < 256) s_scan[tid] += add;
    __syncthreads();
  }
  if (tid < 256) {
    const int base = 2048 - 8 * (tid + 1);
    int s2 = 0;
#pragma unroll
    for (int j = 0; j < 8; ++j) s2 += s_hist[base + j];
    const int above = s_scan[tid] - s2;  // count in bins above my chunk
    int cum = above;
    for (int j = 7; j >= 0; --j) {       // unique crossing: cum < K <= cum+c
      const int c = s_hist[base + j];
      if (cum < K && cum + c >= K) s_tbin = base + j;
      cum += c;
    }
  }
  __syncthreads();
  const unsigned tbin = (unsigned)s_tbin;

  // pass 2: candidates from the REGISTER cache (~K + lambda)
#pragma unroll
  for (int k = 0; k < 3; ++k) {
    const int i = tid + (k << 10);
    if (i < kM4) {
      const unsigned xs[4] = {cache[k].x, cache[k].y, cache[k].z, cache[k].w};
#pragma unroll
      for (int j = 0; j < 4; ++j) {
        const unsigned x = xs[j];
        if (x >= 0x40000000u && mask_bin(x) >= tbin) {
          const int p = atomicAdd(&s_cnt, 1);
          if (p < 1024)
            s_cand[p] = ((unsigned long long)x << 32) |
                        (unsigned)(0xFFFFFFFFu - (unsigned)(4 * i + j));
        }
      }
    }
  }
  __syncthreads();
  const int Nc = imin(s_cnt, 1024);

  // exact rank among candidates (keys pairwise distinct)
  for (int j = tid; j < Nc; j += 1024) {
    const unsigned long long key = s_cand[j];
    int rank = 0;
    for (int i = 0; i < Nc; ++i) rank += (s_cand[i] > key) ? 1 : 0;
    if (rank < K)
      dst[rank] = (int)(0xFFFFFFFFu - (unsigned)(key & 0xFFFFFFFFull));
  }
}

// ---------------------------------------------------------------------------
// Kernel C: one WAVE per output roi (4096 waves, 1024 blocks x 256).
// (round-7 verified, byte-identical)
// ---------------------------------------------------------------------------
__global__ __launch_bounds__(256) void k_final(const float* __restrict__ all_rois,
                                               const float* __restrict__ gt_boxes,
                                               const int* __restrict__ topidx,
                                               const int* __restrict__ nin,
                                               float* __restrict__ out) {
  const int lane = threadIdx.x & 63;
  const int idx = (blockIdx.x << 2) | (threadIdx.x >> 6);  // roi id 0..4095
  const int b = idx >> 8;
  const int pos = idx & 255;

  const int fgc = imin(nin[b], kFgQuota);
  const int bgav = imin(imax(nin[kB + b], 1), kR);
  const bool isfg = pos < fgc;
  int keep;
  if (isfg) keep = topidx[(size_t)b * kR + imin(pos, imax(fgc - 1, 0))];
  else      keep = topidx[(size_t)(kB + b) * kR + (pos - fgc) % bgav];

  const float* bp = (keep < kN) ? (all_rois + ((size_t)b * kN + keep) * 5 + 1)
                                : (gt_boxes + ((size_t)b * kG + (keep - kN)) * 5);
  const float bx0 = bp[0], by0 = bp[1], bx1 = bp[2], by1 = bp[3];
  const float areab = ((bx1 - bx0) + 1.0f) * ((by1 - by0) + 1.0f);

  unsigned long long best = 0ull;
#pragma unroll
  for (int h = 0; h < 2; ++h) {
    const int g = lane + 64 * h;
    const float* gp = gt_boxes + ((size_t)b * kG + g) * 5;
    const float gx0 = gp[0], gy0 = gp[1], gx1 = gp[2], gy1 = gp[3];
    const float ga = ((gx1 - gx0) + 1.0f) * ((gy1 - gy0) + 1.0f);
    const float xx0 = fmaxf(bx0, gx0);
    const float yy0 = fmaxf(by0, gy0);
    const float xx1 = fminf(bx1, gx1);
    const float yy1 = fminf(by1, gy1);
    const float iw = fmaxf((xx1 - xx0) + 1.0f, 0.0f);
    const float ih = fmaxf((yy1 - yy0) + 1.0f, 0.0f);
    const float inter = iw * ih;
    const float iou = inter / ((areab + ga) - inter);   // ref-exact f32 div
    const unsigned long long key =
        ((unsigned long long)__float_as_uint(iou) << 7) | (unsigned)(127 - g);
    if (key > best) best = key;
  }
#pragma unroll
  for (int off = 1; off < 64; off <<= 1) {
    const unsigned long long o = __shfl_xor(best, off, 64);
    if (o > best) best = o;
  }
  const int a = 127 - (int)(best & 127ull);

  const float* gp = gt_boxes + ((size_t)b * kG + a) * 5;
  const float gx0 = gp[0], gy0 = gp[1], gx1 = gp[2], gy1 = gp[3];
  const float lab = isfg ? gp[4] : 0.0f;
  const float fg4 = (lab > 0.0f) ? 1.0f : 0.0f;

  const float ew = (bx1 - bx0) + 1.0f;
  const float eh = (by1 - by0) + 1.0f;
  const float ecx = bx0 + 0.5f * ew;
  const float ecy = by0 + 0.5f * eh;
  const float gw = (gx1 - gx0) + 1.0f;
  const float gh = (gy1 - gy0) + 1.0f;
  const float gcx = gx0 + 0.5f * gw;
  const float gcy = gy0 + 0.5f * gh;
  const float t0 = ((gcx - ecx) / ew) / 0.1f;
  const float t1 = ((gcy - ecy) / eh) / 0.1f;
  const float t2 = logf(gw / ew) / 0.2f;
  const float t3 = logf(gh / eh) / 0.2f;

  if (lane == 0) {
    float* o_rois = out;                                   // [B,R,5]
    float* o_lab  = out + (size_t)kB * kR * 5;             // [B,R]
    float* o_tgt  = o_lab + (size_t)kB * kR;               // [B,R,4]
    float* o_iw   = o_tgt + (size_t)kB * kR * 4;           // [B,R,4]
    float* o_ow   = o_iw  + (size_t)kB * kR * 4;           // [B,R,4]
    const size_t p = (size_t)b * kR + pos;
    o_rois[p * 5 + 0] = (float)b;
    o_rois[p * 5 + 1] = bx0;
    o_rois[p * 5 + 2] = by0;
    o_rois[p * 5 + 3] = bx1;
    o_rois[p * 5 + 4] = by1;
    o_lab[p] = lab;
    o_tgt[p * 4 + 0] = t0 * fg4;
    o_tgt[p * 4 + 1] = t1 * fg4;
    o_tgt[p * 4 + 2] = t2 * fg4;
    o_tgt[p * 4 + 3] = t3 * fg4;
    o_iw[p * 4 + 0] = fg4; o_iw[p * 4 + 1] = fg4;
    o_iw[p * 4 + 2] = fg4; o_iw[p * 4 + 3] = fg4;
    o_ow[p * 4 + 0] = fg4; o_ow[p * 4 + 1] = fg4;
    o_ow[p * 4 + 2] = fg4; o_ow[p * 4 + 3] = fg4;
  }
}

extern "C" void kernel_launch(void* const* d_in, const int* in_sizes, int n_in_args,
                              void* d_out, int out_size, void* d_ws, size_t ws_size,
                              hipStream_t stream) {
  (void)in_sizes; (void)n_in_args; (void)out_size; (void)ws_size;
  const float* all_rois = (const float*)d_in[0];  // [16,12000,5] fp32
  const float* gt_boxes = (const float*)d_in[1];  // [16,128,5] fp32
  float* out = (float*)d_out;

  char* ws = (char*)d_ws;
  unsigned* vb = (unsigned*)ws;                   // 2*kB*kM u32 = 1552384 B
  int* topidx  = (int*)(ws + 1572864);            // 2*kB*kR int = 32 KB
  int* nin     = (int*)(ws + 1572864 + 32768);    // 32 int

  dim3 gA((kM + 127) / 128, kB);                  // (95, 16) = 1520 blocks
  k_prep<<<gA, 256, 0, stream>>>(all_rois, gt_boxes, vb);
  dim3 gB(2, kB);
  k_select<<<gB, 1024, 0, stream>>>(vb, topidx, nin);
  k_final<<<1024, 256, 0, stream>>>(all_rois, gt_boxes, topidx, nin, out);
}